// Round 10
// baseline (1235.338 us; speedup 1.0000x reference)
//
#include <hip/hip_runtime.h>
#include <cmath>

#define BB   64
#define SEQ  1024
#define DD   256
#define HH   32
#define G4   128   // 4*H
#define VV   2048

// fast sigmoid (round-2-proven numerics): e^x/(1+e^x) = 1 - 1/(1+e^x)
__device__ __forceinline__ float fsigm(float x) {
    return 1.0f - __builtin_amdgcn_rcpf(1.0f + __expf(x));
}
// fast tanh: 1 - 2/(1+e^(2x))
__device__ __forceinline__ float ftanh(float x) {
    return 1.0f - 2.0f * __builtin_amdgcn_rcpf(1.0f + __expf(2.0f * x));
}

// y[l] = x[l^32] via v_permlane32_swap.
// With old=src=x: r[0] = [x_lo|x_lo], r[1] = [x_hi|x_hi].
// Lane l<32 wants x[l+32] -> r[1][l]; lane l>=32 wants x[l-32] -> r[0][l].
// (r8/r9 had the selector inverted -> identity -> saturated recurrence,
//  identical 3.62e-4 absmax across numerically different builds.)
__device__ __forceinline__ float lane_xor32(float x, int half) {
#if __has_builtin(__builtin_amdgcn_permlane32_swap)
    auto r = __builtin_amdgcn_permlane32_swap(__float_as_uint(x), __float_as_uint(x),
                                              false, false);
    return __uint_as_float(half ? r[0] : r[1]);
#else
    return __shfl_xor(x, 32, 64);
#endif
}

// ---- 32 named scalar floats per weight row: direct asm operands ------------
#define DECLW32(p) \
    float p##0,p##1,p##2,p##3,p##4,p##5,p##6,p##7, \
          p##8,p##9,p##10,p##11,p##12,p##13,p##14,p##15, \
          p##16,p##17,p##18,p##19,p##20,p##21,p##22,p##23, \
          p##24,p##25,p##26,p##27,p##28,p##29,p##30,p##31

#define LOADW32(p, base, row) do { \
    const float4* _q = (const float4*)&(base)[(row) * HH]; float4 _t; \
    _t=_q[0]; p##0 =_t.x; p##1 =_t.y; p##2 =_t.z; p##3 =_t.w; \
    _t=_q[1]; p##4 =_t.x; p##5 =_t.y; p##6 =_t.z; p##7 =_t.w; \
    _t=_q[2]; p##8 =_t.x; p##9 =_t.y; p##10=_t.z; p##11=_t.w; \
    _t=_q[3]; p##12=_t.x; p##13=_t.y; p##14=_t.z; p##15=_t.w; \
    _t=_q[4]; p##16=_t.x; p##17=_t.y; p##18=_t.z; p##19=_t.w; \
    _t=_q[5]; p##20=_t.x; p##21=_t.y; p##22=_t.z; p##23=_t.w; \
    _t=_q[6]; p##24=_t.x; p##25=_t.y; p##26=_t.z; p##27=_t.w; \
    _t=_q[7]; p##28=_t.x; p##29=_t.y; p##30=_t.z; p##31=_t.w; \
} while (0)

// tied scalar-float asm: defines the values, making remat from memory illegal
#define PIN32(p) do { \
    asm volatile("" : "+v"(p##0),"+v"(p##1),"+v"(p##2),"+v"(p##3), \
                      "+v"(p##4),"+v"(p##5),"+v"(p##6),"+v"(p##7)); \
    asm volatile("" : "+v"(p##8),"+v"(p##9),"+v"(p##10),"+v"(p##11), \
                      "+v"(p##12),"+v"(p##13),"+v"(p##14),"+v"(p##15)); \
    asm volatile("" : "+v"(p##16),"+v"(p##17),"+v"(p##18),"+v"(p##19), \
                      "+v"(p##20),"+v"(p##21),"+v"(p##22),"+v"(p##23)); \
    asm volatile("" : "+v"(p##24),"+v"(p##25),"+v"(p##26),"+v"(p##27), \
                      "+v"(p##28),"+v"(p##29),"+v"(p##30),"+v"(p##31)); \
} while (0)

#define DECLH8(h) float4 h##0, h##1, h##2, h##3, h##4, h##5, h##6, h##7
#define LOADH(h, src) do { \
    h##0=(src)[0]; h##1=(src)[1]; h##2=(src)[2]; h##3=(src)[3]; \
    h##4=(src)[4]; h##5=(src)[5]; h##6=(src)[6]; h##7=(src)[7]; \
} while (0)
#define ZEROH(h) do { \
    h##0=h##1=h##2=h##3=h##4=h##5=h##6=h##7=make_float4(0.f,0.f,0.f,0.f); \
} while (0)

// 32-long dot: scalar weights x float4 h-quads, 4 independent chains.
#define DOT32S(res, P, Q) do { \
    float _a0=0.f,_a1=0.f,_a2=0.f,_a3=0.f; \
    _a0=fmaf(P##3 ,(Q##0).w,fmaf(P##2 ,(Q##0).z,fmaf(P##1 ,(Q##0).y,fmaf(P##0 ,(Q##0).x,_a0)))); \
    _a1=fmaf(P##7 ,(Q##1).w,fmaf(P##6 ,(Q##1).z,fmaf(P##5 ,(Q##1).y,fmaf(P##4 ,(Q##1).x,_a1)))); \
    _a2=fmaf(P##11,(Q##2).w,fmaf(P##10,(Q##2).z,fmaf(P##9 ,(Q##2).y,fmaf(P##8 ,(Q##2).x,_a2)))); \
    _a3=fmaf(P##15,(Q##3).w,fmaf(P##14,(Q##3).z,fmaf(P##13,(Q##3).y,fmaf(P##12,(Q##3).x,_a3)))); \
    _a0=fmaf(P##19,(Q##4).w,fmaf(P##18,(Q##4).z,fmaf(P##17,(Q##4).y,fmaf(P##16,(Q##4).x,_a0)))); \
    _a1=fmaf(P##23,(Q##5).w,fmaf(P##22,(Q##5).z,fmaf(P##21,(Q##5).y,fmaf(P##20,(Q##5).x,_a1)))); \
    _a2=fmaf(P##27,(Q##6).w,fmaf(P##26,(Q##6).z,fmaf(P##25,(Q##6).y,fmaf(P##24,(Q##6).x,_a2)))); \
    _a3=fmaf(P##31,(Q##7).w,fmaf(P##30,(Q##7).z,fmaf(P##29,(Q##7).y,fmaf(P##28,(Q##7).x,_a3)))); \
    res=(_a0+_a1)+(_a2+_a3); \
} while (0)

// ---------------------------------------------------------------------------
// Kernel A1: emb_proj[v][j] = b_ih1[j]+b_hh1[j] + sum_d emb[v][d]*W_ih1[j][d]
// ---------------------------------------------------------------------------
__global__ __launch_bounds__(128) void emb_proj_kernel(
    const float* __restrict__ emb, const float* __restrict__ W_ih1,
    const float* __restrict__ b_ih1, const float* __restrict__ b_hh1,
    float* __restrict__ emb_proj)
{
    const int v = blockIdx.x;
    const int j = threadIdx.x;
    __shared__ __align__(16) float ev[DD];
    ev[j]       = emb[v * DD + j];
    ev[j + 128] = emb[v * DD + 128 + j];
    __syncthreads();
    float acc = b_ih1[j] + b_hh1[j];
#pragma unroll 8
    for (int q = 0; q < DD / 4; ++q) {
        float4 w = *(const float4*)&W_ih1[j * DD + 4 * q];
        float4 e = *(const float4*)&ev[4 * q];
        acc += w.x * e.x + w.y * e.y + w.z * e.z + w.w * e.w;
    }
    emb_proj[v * G4 + j] = acc;
}

// ---------------------------------------------------------------------------
// Kernel A2: W_fcT[k][v] = W_fc[v][k]
// ---------------------------------------------------------------------------
__global__ __launch_bounds__(256) void transpose_wfc_kernel(
    const float* __restrict__ W_fc, float* __restrict__ W_fcT)
{
    int i = blockIdx.x * 256 + threadIdx.x;
    int v = i >> 5;
    int k = i & 31;
    W_fcT[k * VV + v] = W_fc[i];
}

// ---------------------------------------------------------------------------
// Kernel B: 2-layer LSTM recurrence, one wave per batch element.
// Lane l owns gate rows r0=l, r1=l+64 (rows: 0-31 i, 32-63 f, 64-95 g, 96-127 o).
// 192 weight floats pinned in VGPRs via scalar tied-asm. h broadcast via LDS
// uniform ds_read_b128. Gate half-exchange via v_permlane32_swap (fixed sel).
// ---------------------------------------------------------------------------
__global__ __launch_bounds__(64, 1) void lstm_rec_wave_kernel(
    const int* __restrict__ x_ids, const float* __restrict__ emb_proj,
    const float* __restrict__ W_hh1, const float* __restrict__ W_ih2,
    const float* __restrict__ W_hh2, const float* __restrict__ b_ih2,
    const float* __restrict__ b_hh2, float* __restrict__ h2_all)
{
    const int b = blockIdx.x;
    const int l = threadIdx.x;      // 0..63
    const int half = l >> 5;
    const int r0 = l;
    const int r1 = l + 64;

    // r0 rows (i or f): sigmoid. r1 rows: g (tanh) on half0, o (sigm) on half1.
    const float a1  = half ? 1.0f : 2.0f;   // exp argument scale for r1 act
    const float c1p = half ? 1.0f : 2.0f;   // rcp coefficient for r1 act

    DECLW32(w11a); DECLW32(w11b); DECLW32(w21a);
    DECLW32(w21b); DECLW32(w22a); DECLW32(w22b);
    LOADW32(w11a, W_hh1, r0); LOADW32(w11b, W_hh1, r1);
    LOADW32(w21a, W_ih2, r0); LOADW32(w21b, W_ih2, r1);
    LOADW32(w22a, W_hh2, r0); LOADW32(w22b, W_hh2, r1);
    PIN32(w11a); PIN32(w11b); PIN32(w21a);
    PIN32(w21b); PIN32(w22a); PIN32(w22b);

    const float bias20 = b_ih2[r0] + b_hh2[r0];
    const float bias21 = b_ih2[r1] + b_hh2[r1];

    __shared__ __align__(16) float h1s[HH];
    __shared__ __align__(16) float h2s[HH];
    const float4* h1v = (const float4*)h1s;
    const float4* h2v = (const float4*)h2s;

    DECLH8(h1q); DECLH8(h2q);
    ZEROH(h1q); ZEROH(h2q);

    float c1 = 0.0f, c2 = 0.0f;

    const int* ids = x_ids + b * SEQ;
    int idn = ids[1];
    float ep0 = emb_proj[ids[0] * G4 + r0];
    float ep1 = emb_proj[ids[0] * G4 + r1];

    float* h2out = h2_all + (long)b * SEQ * HH + l;

    for (int t = 0; t < SEQ; ++t) {
        // prefetch next step's emb_proj row + id two steps ahead (hidden)
        const float ep0n = emb_proj[idn * G4 + r0];
        const float ep1n = emb_proj[idn * G4 + r1];
        const int tn2 = (t + 2 < SEQ) ? (t + 2) : (SEQ - 1);
        const int idn2 = ids[tn2];

        // ---- layer 1 gates: ep + W_hh1 @ h1(prev) ----
        float d0, d1;
        DOT32S(d0, w11a, h1q);
        DOT32S(d1, w11b, h1q);
        const float gr0 = ep0 + d0;
        const float gr1 = ep1 + d1;

        const float A0 = fsigm(gr0);
        const float A1 = 1.0f - c1p * __builtin_amdgcn_rcpf(1.0f + __expf(a1 * gr1));
        const float B0 = lane_xor32(A0, half);
        const float B1 = lane_xor32(A1, half);
        const float gi = half ? B0 : A0;
        const float gf = half ? A0 : B0;
        const float gg = half ? B1 : A1;
        const float go = half ? A1 : B1;

        c1 = gf * c1 + gi * gg;
        const float h1n = go * ftanh(c1);

        // publish h1, immediately issue broadcast reads (latency hidden under
        // the independent W_hh2 @ h2(prev) dots)
        if (l < HH) h1s[l] = h1n;
        LOADH(h1q, h1v);

        float p0, p1;
        DOT32S(p0, w22a, h2q);
        DOT32S(p1, w22b, h2q);

        // ---- layer 2 gates ----
        float e0, e1;
        DOT32S(e0, w21a, h1q);
        DOT32S(e1, w21b, h1q);
        const float qr0 = bias20 + p0 + e0;
        const float qr1 = bias21 + p1 + e1;

        const float C0 = fsigm(qr0);
        const float C1 = 1.0f - c1p * __builtin_amdgcn_rcpf(1.0f + __expf(a1 * qr1));
        const float D0 = lane_xor32(C0, half);
        const float D1 = lane_xor32(C1, half);
        const float pi = half ? D0 : C0;
        const float pf = half ? C0 : D0;
        const float pg = half ? D1 : C1;
        const float po = half ? C1 : D1;

        c2 = pf * c2 + pi * pg;
        const float h2n = po * ftanh(c2);

        if (l < HH) { h2s[l] = h2n; h2out[t * HH] = h2n; }
        // broadcast h2 for next step (latency hides under next layer-1 dots)
        LOADH(h2q, h2v);

        ep0 = ep0n; ep1 = ep1n; idn = idn2;
    }
}

// ---------------------------------------------------------------------------
// Kernel C: logits = h2 @ W_fc^T + b_fc, row softmax, write [B*S][V].
// 16 rows per block, 256 threads, thread owns 8 contiguous vocab cols.
// ---------------------------------------------------------------------------
__global__ __launch_bounds__(256, 1) void fc_softmax_kernel(
    const float* __restrict__ h2_all, const float* __restrict__ W_fcT,
    const float* __restrict__ b_fc, float* __restrict__ out)
{
    const int tid = threadIdx.x;
    const long rowbase = (long)blockIdx.x * 16;
    __shared__ __align__(16) float h2t[16][HH];
    __shared__ float wred[16][4];

    ((float*)h2t)[tid]       = h2_all[rowbase * HH + tid];
    ((float*)h2t)[tid + 256] = h2_all[rowbase * HH + tid + 256];
    __syncthreads();

    const int v0 = tid * 8;
    const float4 bf0 = *(const float4*)&b_fc[v0];
    const float4 bf1 = *(const float4*)&b_fc[v0 + 4];
    float acc[16][8];
#pragma unroll
    for (int r = 0; r < 16; ++r) {
        acc[r][0] = bf0.x; acc[r][1] = bf0.y; acc[r][2] = bf0.z; acc[r][3] = bf0.w;
        acc[r][4] = bf1.x; acc[r][5] = bf1.y; acc[r][6] = bf1.z; acc[r][7] = bf1.w;
    }

#pragma unroll
    for (int kq = 0; kq < 8; ++kq) {
        const int k = kq * 4;
        float4 wa[4], wb[4];
#pragma unroll
        for (int i = 0; i < 4; ++i) {
            wa[i] = *(const float4*)&W_fcT[(k + i) * VV + v0];
            wb[i] = *(const float4*)&W_fcT[(k + i) * VV + v0 + 4];
        }
#pragma unroll
        for (int r = 0; r < 16; ++r) {
            const float4 h = *(const float4*)&h2t[r][k];
            const float hh[4] = {h.x, h.y, h.z, h.w};
#pragma unroll
            for (int i = 0; i < 4; ++i) {
                acc[r][0] += hh[i] * wa[i].x; acc[r][1] += hh[i] * wa[i].y;
                acc[r][2] += hh[i] * wa[i].z; acc[r][3] += hh[i] * wa[i].w;
                acc[r][4] += hh[i] * wb[i].x; acc[r][5] += hh[i] * wb[i].y;
                acc[r][6] += hh[i] * wb[i].z; acc[r][7] += hh[i] * wb[i].w;
            }
        }
    }

    const int wv = tid >> 6;
    const int lane = tid & 63;

    float m[16];
#pragma unroll
    for (int r = 0; r < 16; ++r) {
        float v = acc[r][0];
#pragma unroll
        for (int c = 1; c < 8; ++c) v = fmaxf(v, acc[r][c]);
#pragma unroll
        for (int s = 32; s >= 1; s >>= 1) v = fmaxf(v, __shfl_xor(v, s, 64));
        m[r] = v;
    }
    if (lane == 0) {
#pragma unroll
        for (int r = 0; r < 16; ++r) wred[r][wv] = m[r];
    }
    __syncthreads();
    float rm[16];
#pragma unroll
    for (int r = 0; r < 16; ++r)
        rm[r] = fmaxf(fmaxf(wred[r][0], wred[r][1]), fmaxf(wred[r][2], wred[r][3]));
    __syncthreads();

    float s[16];
#pragma unroll
    for (int r = 0; r < 16; ++r) {
        float sum = 0.0f;
#pragma unroll
        for (int c = 0; c < 8; ++c) {
            float e = __expf(acc[r][c] - rm[r]);
            acc[r][c] = e;
            sum += e;
        }
#pragma unroll
        for (int st = 32; st >= 1; st >>= 1) sum += __shfl_xor(sum, st, 64);
        s[r] = sum;
    }
    if (lane == 0) {
#pragma unroll
        for (int r = 0; r < 16; ++r) wred[r][wv] = s[r];
    }
    __syncthreads();

#pragma unroll
    for (int r = 0; r < 16; ++r) {
        const float rs = wred[r][0] + wred[r][1] + wred[r][2] + wred[r][3];
        const float inv = 1.0f / rs;
        float4 o0 = make_float4(acc[r][0] * inv, acc[r][1] * inv, acc[r][2] * inv, acc[r][3] * inv);
        float4 o1 = make_float4(acc[r][4] * inv, acc[r][5] * inv, acc[r][6] * inv, acc[r][7] * inv);
        float* op = out + (rowbase + r) * VV + v0;
        *(float4*)op = o0;
        *(float4*)(op + 4) = o1;
    }
}

// ---------------------------------------------------------------------------
extern "C" void kernel_launch(void* const* d_in, const int* in_sizes, int n_in,
                              void* d_out, int out_size, void* d_ws, size_t ws_size,
                              hipStream_t stream)
{
    const int*   x_ids = (const int*)d_in[0];
    const float* emb   = (const float*)d_in[1];
    const float* W_ih1 = (const float*)d_in[2];
    const float* W_hh1 = (const float*)d_in[3];
    const float* b_ih1 = (const float*)d_in[4];
    const float* b_hh1 = (const float*)d_in[5];
    const float* W_ih2 = (const float*)d_in[6];
    const float* W_hh2 = (const float*)d_in[7];
    const float* b_ih2 = (const float*)d_in[8];
    const float* b_hh2 = (const float*)d_in[9];
    const float* W_fc  = (const float*)d_in[10];
    const float* b_fc  = (const float*)d_in[11];
    float* out = (float*)d_out;

    float* ws = (float*)d_ws;
    float* emb_proj = ws;                         // V*4H   = 262144
    float* W_fcT    = ws + 262144;                // H*V    = 65536
    float* h2_all   = ws + 262144 + 65536;        // B*S*H  = 2097152

    emb_proj_kernel<<<VV, 128, 0, stream>>>(emb, W_ih1, b_ih1, b_hh1, emb_proj);
    transpose_wfc_kernel<<<(VV * HH) / 256, 256, 0, stream>>>(W_fc, W_fcT);
    lstm_rec_wave_kernel<<<BB, 64, 0, stream>>>(x_ids, emb_proj, W_hh1, W_ih2, W_hh2,
                                                b_ih2, b_hh2, h2_all);
    fc_softmax_kernel<<<(BB * SEQ) / 16, 256, 0, stream>>>(h2_all, W_fcT, b_fc, out);
}

// Round 11
// 1093.438 us; speedup vs baseline: 1.1298x; 1.1298x over previous
//
#include <hip/hip_runtime.h>
#include <cmath>

#define BB   64
#define SEQ  1024
#define DD   256
#define HH   32
#define G4   128   // 4*H
#define VV   2048

// fast sigmoid: e^x/(1+e^x) = 1 - 1/(1+e^x)
__device__ __forceinline__ float fsigm(float x) {
    return 1.0f - __builtin_amdgcn_rcpf(1.0f + __expf(x));
}
// fast tanh: 1 - 2/(1+e^(2x))
__device__ __forceinline__ float ftanh(float x) {
    return 1.0f - 2.0f * __builtin_amdgcn_rcpf(1.0f + __expf(2.0f * x));
}

// y[l] = x[l^32] via v_permlane32_swap. With old=src=x:
// r[0]=[x_lo|x_lo], r[1]=[x_hi|x_hi]; lane<32 wants x_hi -> r[1], lane>=32 -> r[0].
__device__ __forceinline__ float lane_xor32(float x, int half) {
#if __has_builtin(__builtin_amdgcn_permlane32_swap)
    auto r = __builtin_amdgcn_permlane32_swap(__float_as_uint(x), __float_as_uint(x),
                                              false, false);
    return __uint_as_float(half ? r[0] : r[1]);
#else
    return __shfl_xor(x, 32, 64);
#endif
}

// ---- 32 named scalar floats per weight row: direct asm operands ------------
#define DECLW32(p) \
    float p##0,p##1,p##2,p##3,p##4,p##5,p##6,p##7, \
          p##8,p##9,p##10,p##11,p##12,p##13,p##14,p##15, \
          p##16,p##17,p##18,p##19,p##20,p##21,p##22,p##23, \
          p##24,p##25,p##26,p##27,p##28,p##29,p##30,p##31

#define LOADW32(p, base, row) do { \
    const float4* _q = (const float4*)&(base)[(row) * HH]; float4 _t; \
    _t=_q[0]; p##0 =_t.x; p##1 =_t.y; p##2 =_t.z; p##3 =_t.w; \
    _t=_q[1]; p##4 =_t.x; p##5 =_t.y; p##6 =_t.z; p##7 =_t.w; \
    _t=_q[2]; p##8 =_t.x; p##9 =_t.y; p##10=_t.z; p##11=_t.w; \
    _t=_q[3]; p##12=_t.x; p##13=_t.y; p##14=_t.z; p##15=_t.w; \
    _t=_q[4]; p##16=_t.x; p##17=_t.y; p##18=_t.z; p##19=_t.w; \
    _t=_q[5]; p##20=_t.x; p##21=_t.y; p##22=_t.z; p##23=_t.w; \
    _t=_q[6]; p##24=_t.x; p##25=_t.y; p##26=_t.z; p##27=_t.w; \
    _t=_q[7]; p##28=_t.x; p##29=_t.y; p##30=_t.z; p##31=_t.w; \
} while (0)

// tied scalar-float asm: keeps values as asm-defined (no remat from memory)
#define PIN32(p) do { \
    asm volatile("" : "+v"(p##0),"+v"(p##1),"+v"(p##2),"+v"(p##3), \
                      "+v"(p##4),"+v"(p##5),"+v"(p##6),"+v"(p##7)); \
    asm volatile("" : "+v"(p##8),"+v"(p##9),"+v"(p##10),"+v"(p##11), \
                      "+v"(p##12),"+v"(p##13),"+v"(p##14),"+v"(p##15)); \
    asm volatile("" : "+v"(p##16),"+v"(p##17),"+v"(p##18),"+v"(p##19), \
                      "+v"(p##20),"+v"(p##21),"+v"(p##22),"+v"(p##23)); \
    asm volatile("" : "+v"(p##24),"+v"(p##25),"+v"(p##26),"+v"(p##27), \
                      "+v"(p##28),"+v"(p##29),"+v"(p##30),"+v"(p##31)); \
} while (0)

#define DECLH8(h) float4 h##0, h##1, h##2, h##3, h##4, h##5, h##6, h##7
#define LOADH(h, src) do { \
    h##0=(src)[0]; h##1=(src)[1]; h##2=(src)[2]; h##3=(src)[3]; \
    h##4=(src)[4]; h##5=(src)[5]; h##6=(src)[6]; h##7=(src)[7]; \
} while (0)
#define ZEROH(h) do { \
    h##0=h##1=h##2=h##3=h##4=h##5=h##6=h##7=make_float4(0.f,0.f,0.f,0.f); \
} while (0)

// 32-long dot: scalar weights x float4 h-quads, 4 independent chains.
#define DOT32S(res, P, Q) do { \
    float _a0=0.f,_a1=0.f,_a2=0.f,_a3=0.f; \
    _a0=fmaf(P##3 ,(Q##0).w,fmaf(P##2 ,(Q##0).z,fmaf(P##1 ,(Q##0).y,fmaf(P##0 ,(Q##0).x,_a0)))); \
    _a1=fmaf(P##7 ,(Q##1).w,fmaf(P##6 ,(Q##1).z,fmaf(P##5 ,(Q##1).y,fmaf(P##4 ,(Q##1).x,_a1)))); \
    _a2=fmaf(P##11,(Q##2).w,fmaf(P##10,(Q##2).z,fmaf(P##9 ,(Q##2).y,fmaf(P##8 ,(Q##2).x,_a2)))); \
    _a3=fmaf(P##15,(Q##3).w,fmaf(P##14,(Q##3).z,fmaf(P##13,(Q##3).y,fmaf(P##12,(Q##3).x,_a3)))); \
    _a0=fmaf(P##19,(Q##4).w,fmaf(P##18,(Q##4).z,fmaf(P##17,(Q##4).y,fmaf(P##16,(Q##4).x,_a0)))); \
    _a1=fmaf(P##23,(Q##5).w,fmaf(P##22,(Q##5).z,fmaf(P##21,(Q##5).y,fmaf(P##20,(Q##5).x,_a1)))); \
    _a2=fmaf(P##27,(Q##6).w,fmaf(P##26,(Q##6).z,fmaf(P##25,(Q##6).y,fmaf(P##24,(Q##6).x,_a2)))); \
    _a3=fmaf(P##31,(Q##7).w,fmaf(P##30,(Q##7).z,fmaf(P##29,(Q##7).y,fmaf(P##28,(Q##7).x,_a3)))); \
    res=(_a0+_a1)+(_a2+_a3); \
} while (0)

// ---------------------------------------------------------------------------
// Kernel A1: emb_proj[v][j] = b_ih1[j]+b_hh1[j] + sum_d emb[v][d]*W_ih1[j][d]
// ---------------------------------------------------------------------------
__global__ __launch_bounds__(128) void emb_proj_kernel(
    const float* __restrict__ emb, const float* __restrict__ W_ih1,
    const float* __restrict__ b_ih1, const float* __restrict__ b_hh1,
    float* __restrict__ emb_proj)
{
    const int v = blockIdx.x;
    const int j = threadIdx.x;
    __shared__ __align__(16) float ev[DD];
    ev[j]       = emb[v * DD + j];
    ev[j + 128] = emb[v * DD + 128 + j];
    __syncthreads();
    float acc = b_ih1[j] + b_hh1[j];
#pragma unroll 8
    for (int q = 0; q < DD / 4; ++q) {
        float4 w = *(const float4*)&W_ih1[j * DD + 4 * q];
        float4 e = *(const float4*)&ev[4 * q];
        acc += w.x * e.x + w.y * e.y + w.z * e.z + w.w * e.w;
    }
    emb_proj[v * G4 + j] = acc;
}

// ---------------------------------------------------------------------------
// Kernel A2: W_fcT[k][v] = W_fc[v][k]
// ---------------------------------------------------------------------------
__global__ __launch_bounds__(256) void transpose_wfc_kernel(
    const float* __restrict__ W_fc, float* __restrict__ W_fcT)
{
    int i = blockIdx.x * 256 + threadIdx.x;
    int v = i >> 5;
    int k = i & 31;
    W_fcT[k * VV + v] = W_fc[i];
}

// ---------------------------------------------------------------------------
// Kernel B: 2-layer LSTM recurrence, one wave per batch element.
// amdgpu_waves_per_eu(1,1): unlock the full 512-VGPR budget so weights AND
// all in-flight ds_read results stay register-resident (r10 showed the
// allocator's ~140-reg heuristic; suspected consequence: serialized LDS
// round-trips at ~120cy each = the dominant per-step stall).
// ---------------------------------------------------------------------------
__global__ __launch_bounds__(64)
__attribute__((amdgpu_waves_per_eu(1, 1)))
void lstm_rec_wave_kernel(
    const int* __restrict__ x_ids, const float* __restrict__ emb_proj,
    const float* __restrict__ W_hh1, const float* __restrict__ W_ih2,
    const float* __restrict__ W_hh2, const float* __restrict__ b_ih2,
    const float* __restrict__ b_hh2, float* __restrict__ h2_all)
{
    const int b = blockIdx.x;
    const int l = threadIdx.x;      // 0..63
    const int half = l >> 5;
    const int r0 = l;
    const int r1 = l + 64;

    // r0 rows (i or f): sigmoid. r1 rows: g (tanh) on half0, o (sigm) on half1.
    const float a1  = half ? 1.0f : 2.0f;   // exp argument scale for r1 act
    const float c1p = half ? 1.0f : 2.0f;   // rcp coefficient for r1 act

    DECLW32(w11a); DECLW32(w11b); DECLW32(w21a);
    DECLW32(w21b); DECLW32(w22a); DECLW32(w22b);
    LOADW32(w11a, W_hh1, r0); LOADW32(w11b, W_hh1, r1);
    LOADW32(w21a, W_ih2, r0); LOADW32(w21b, W_ih2, r1);
    LOADW32(w22a, W_hh2, r0); LOADW32(w22b, W_hh2, r1);
    PIN32(w11a); PIN32(w11b); PIN32(w21a);
    PIN32(w21b); PIN32(w22a); PIN32(w22b);

    const float bias20 = b_ih2[r0] + b_hh2[r0];
    const float bias21 = b_ih2[r1] + b_hh2[r1];

    __shared__ __align__(16) float h1s[HH];
    __shared__ __align__(16) float h2s[HH];
    const float4* h1v = (const float4*)h1s;
    const float4* h2v = (const float4*)h2s;

    DECLH8(h1q); DECLH8(h2q);
    ZEROH(h1q); ZEROH(h2q);

    float c1 = 0.0f, c2 = 0.0f;

    const int* ids = x_ids + b * SEQ;
    int idn = ids[1];
    float ep0 = emb_proj[ids[0] * G4 + r0];
    float ep1 = emb_proj[ids[0] * G4 + r1];

    float* h2out = h2_all + (long)b * SEQ * HH + l;

    for (int t = 0; t < SEQ; ++t) {
        // prefetch next step's emb_proj row + id two steps ahead (hidden)
        const float ep0n = emb_proj[idn * G4 + r0];
        const float ep1n = emb_proj[idn * G4 + r1];
        const int tn2 = (t + 2 < SEQ) ? (t + 2) : (SEQ - 1);
        const int idn2 = ids[tn2];

        // ---- layer 1 gates: ep + W_hh1 @ h1(prev) ----
        float d0, d1;
        DOT32S(d0, w11a, h1q);
        DOT32S(d1, w11b, h1q);
        const float gr0 = ep0 + d0;
        const float gr1 = ep1 + d1;

        const float A0 = fsigm(gr0);
        const float A1 = 1.0f - c1p * __builtin_amdgcn_rcpf(1.0f + __expf(a1 * gr1));
        const float B0 = lane_xor32(A0, half);
        const float B1 = lane_xor32(A1, half);
        const float gi = half ? B0 : A0;
        const float gf = half ? A0 : B0;
        const float gg = half ? B1 : A1;
        const float go = half ? A1 : B1;

        c1 = gf * c1 + gi * gg;
        const float h1n = go * ftanh(c1);

        // publish h1, immediately issue all broadcast reads (latency hidden
        // under the independent W_hh2 @ h2(prev) dots)
        if (l < HH) h1s[l] = h1n;
        LOADH(h1q, h1v);

        float p0, p1;
        DOT32S(p0, w22a, h2q);
        DOT32S(p1, w22b, h2q);

        // ---- layer 2 gates ----
        float e0, e1;
        DOT32S(e0, w21a, h1q);
        DOT32S(e1, w21b, h1q);
        const float qr0 = bias20 + p0 + e0;
        const float qr1 = bias21 + p1 + e1;

        const float C0 = fsigm(qr0);
        const float C1 = 1.0f - c1p * __builtin_amdgcn_rcpf(1.0f + __expf(a1 * qr1));
        const float D0 = lane_xor32(C0, half);
        const float D1 = lane_xor32(C1, half);
        const float pi = half ? D0 : C0;
        const float pf = half ? C0 : D0;
        const float pg = half ? D1 : C1;
        const float po = half ? C1 : D1;

        c2 = pf * c2 + pi * pg;
        const float h2n = po * ftanh(c2);

        if (l < HH) { h2s[l] = h2n; h2out[t * HH] = h2n; }
        // broadcast h2 for next step (latency hides under next layer-1 dots)
        LOADH(h2q, h2v);

        ep0 = ep0n; ep1 = ep1n; idn = idn2;
    }
}

// ---------------------------------------------------------------------------
// Kernel C: logits = h2 @ W_fc^T + b_fc, row softmax, write [B*S][V].
// r1-proven config: 8 rows/block, 256 threads, 8 vocab cols/thread.
// (16-row variant regressed ~150µs: acc[16][8] register pressure + (256,1)
// launch bound dropped occupancy — reverted.)
// ---------------------------------------------------------------------------
__global__ __launch_bounds__(256) void fc_softmax_kernel(
    const float* __restrict__ h2_all, const float* __restrict__ W_fcT,
    const float* __restrict__ b_fc, float* __restrict__ out)
{
    const int tid = threadIdx.x;
    const long rowbase = (long)blockIdx.x * 8;
    __shared__ __align__(16) float h2t[8][HH];
    __shared__ float wred[8][4];

    h2t[tid >> 5][tid & 31] = h2_all[rowbase * HH + tid];
    __syncthreads();

    const int v0 = tid * 8;
    const float4 bf0 = *(const float4*)&b_fc[v0];
    const float4 bf1 = *(const float4*)&b_fc[v0 + 4];
    float acc[8][8];
#pragma unroll
    for (int r = 0; r < 8; ++r) {
        acc[r][0] = bf0.x; acc[r][1] = bf0.y; acc[r][2] = bf0.z; acc[r][3] = bf0.w;
        acc[r][4] = bf1.x; acc[r][5] = bf1.y; acc[r][6] = bf1.z; acc[r][7] = bf1.w;
    }

#pragma unroll
    for (int kq = 0; kq < 8; ++kq) {
        const int k = kq * 4;
        float4 wa[4], wb[4];
#pragma unroll
        for (int i = 0; i < 4; ++i) {
            wa[i] = *(const float4*)&W_fcT[(k + i) * VV + v0];
            wb[i] = *(const float4*)&W_fcT[(k + i) * VV + v0 + 4];
        }
#pragma unroll
        for (int r = 0; r < 8; ++r) {
            const float4 h = *(const float4*)&h2t[r][k];
            const float hh[4] = {h.x, h.y, h.z, h.w};
#pragma unroll
            for (int i = 0; i < 4; ++i) {
                acc[r][0] += hh[i] * wa[i].x; acc[r][1] += hh[i] * wa[i].y;
                acc[r][2] += hh[i] * wa[i].z; acc[r][3] += hh[i] * wa[i].w;
                acc[r][4] += hh[i] * wb[i].x; acc[r][5] += hh[i] * wb[i].y;
                acc[r][6] += hh[i] * wb[i].z; acc[r][7] += hh[i] * wb[i].w;
            }
        }
    }

    const int wv = tid >> 6;
    const int lane = tid & 63;

    float m[8];
#pragma unroll
    for (int r = 0; r < 8; ++r) {
        float v = acc[r][0];
#pragma unroll
        for (int c = 1; c < 8; ++c) v = fmaxf(v, acc[r][c]);
#pragma unroll
        for (int s = 32; s >= 1; s >>= 1) v = fmaxf(v, __shfl_xor(v, s, 64));
        m[r] = v;
    }
    if (lane == 0) {
#pragma unroll
        for (int r = 0; r < 8; ++r) wred[r][wv] = m[r];
    }
    __syncthreads();
    float rm[8];
#pragma unroll
    for (int r = 0; r < 8; ++r)
        rm[r] = fmaxf(fmaxf(wred[r][0], wred[r][1]), fmaxf(wred[r][2], wred[r][3]));
    __syncthreads();

    float s[8];
#pragma unroll
    for (int r = 0; r < 8; ++r) {
        float sum = 0.0f;
#pragma unroll
        for (int c = 0; c < 8; ++c) {
            float e = __expf(acc[r][c] - rm[r]);
            acc[r][c] = e;
            sum += e;
        }
#pragma unroll
        for (int st = 32; st >= 1; st >>= 1) sum += __shfl_xor(sum, st, 64);
        s[r] = sum;
    }
    if (lane == 0) {
#pragma unroll
        for (int r = 0; r < 8; ++r) wred[r][wv] = s[r];
    }
    __syncthreads();

#pragma unroll
    for (int r = 0; r < 8; ++r) {
        const float rs = wred[r][0] + wred[r][1] + wred[r][2] + wred[r][3];
        const float inv = 1.0f / rs;
        float4 o0 = make_float4(acc[r][0] * inv, acc[r][1] * inv, acc[r][2] * inv, acc[r][3] * inv);
        float4 o1 = make_float4(acc[r][4] * inv, acc[r][5] * inv, acc[r][6] * inv, acc[r][7] * inv);
        float* op = out + (rowbase + r) * VV + v0;
        *(float4*)op = o0;
        *(float4*)(op + 4) = o1;
    }
}

// ---------------------------------------------------------------------------
extern "C" void kernel_launch(void* const* d_in, const int* in_sizes, int n_in,
                              void* d_out, int out_size, void* d_ws, size_t ws_size,
                              hipStream_t stream)
{
    const int*   x_ids = (const int*)d_in[0];
    const float* emb   = (const float*)d_in[1];
    const float* W_ih1 = (const float*)d_in[2];
    const float* W_hh1 = (const float*)d_in[3];
    const float* b_ih1 = (const float*)d_in[4];
    const float* b_hh1 = (const float*)d_in[5];
    const float* W_ih2 = (const float*)d_in[6];
    const float* W_hh2 = (const float*)d_in[7];
    const float* b_ih2 = (const float*)d_in[8];
    const float* b_hh2 = (const float*)d_in[9];
    const float* W_fc  = (const float*)d_in[10];
    const float* b_fc  = (const float*)d_in[11];
    float* out = (float*)d_out;

    float* ws = (float*)d_ws;
    float* emb_proj = ws;                         // V*4H   = 262144
    float* W_fcT    = ws + 262144;                // H*V    = 65536
    float* h2_all   = ws + 262144 + 65536;        // B*S*H  = 2097152

    emb_proj_kernel<<<VV, 128, 0, stream>>>(emb, W_ih1, b_ih1, b_hh1, emb_proj);
    transpose_wfc_kernel<<<(VV * HH) / 256, 256, 0, stream>>>(W_fc, W_fcT);
    lstm_rec_wave_kernel<<<BB, 64, 0, stream>>>(x_ids, emb_proj, W_hh1, W_ih2, W_hh2,
                                                b_ih2, b_hh2, h2_all);
    fc_softmax_kernel<<<(BB * SEQ) / 8, 256, 0, stream>>>(h2_all, W_fcT, b_fc, out);
}

// Round 12
// 1058.329 us; speedup vs baseline: 1.1673x; 1.0332x over previous
//
#include <hip/hip_runtime.h>
#include <cmath>

#define BB   64
#define SEQ  1024
#define DD   256
#define HH   32
#define G4   128   // 4*H
#define VV   2048

// fast sigmoid: e^x/(1+e^x) = 1 - 1/(1+e^x)
__device__ __forceinline__ float fsigm(float x) {
    return 1.0f - __builtin_amdgcn_rcpf(1.0f + __expf(x));
}
// fast tanh: 1 - 2/(1+e^(2x))
__device__ __forceinline__ float ftanh(float x) {
    return 1.0f - 2.0f * __builtin_amdgcn_rcpf(1.0f + __expf(2.0f * x));
}

// y[l] = x[l^32] via v_permlane32_swap (verified r10). With old=src=x:
// r[0]=[x_lo|x_lo], r[1]=[x_hi|x_hi]; lane<32 wants x_hi -> r[1], lane>=32 -> r[0].
__device__ __forceinline__ float lane_xor32(float x, int half) {
#if __has_builtin(__builtin_amdgcn_permlane32_swap)
    auto r = __builtin_amdgcn_permlane32_swap(__float_as_uint(x), __float_as_uint(x),
                                              false, false);
    return __uint_as_float(half ? r[0] : r[1]);
#else
    return __shfl_xor(x, 32, 64);
#endif
}

#define DECLH8(h) float4 h##0, h##1, h##2, h##3, h##4, h##5, h##6, h##7
#define LOADH(h, src) do { \
    h##0=(src)[0]; h##1=(src)[1]; h##2=(src)[2]; h##3=(src)[3]; \
    h##4=(src)[4]; h##5=(src)[5]; h##6=(src)[6]; h##7=(src)[7]; \
} while (0)
#define ZEROH(h) do { \
    h##0=h##1=h##2=h##3=h##4=h##5=h##6=h##7=make_float4(0.f,0.f,0.f,0.f); \
} while (0)

// acc += dot(W, H) for one float4 pair (params uppercase: member tokens are
// lowercase .x/.y/.z/.w, no substitution collision)
#define FMA4F(A, W, H) \
    A = fmaf((W).w, (H).w, fmaf((W).z, (H).z, fmaf((W).y, (H).y, fmaf((W).x, (H).x, A))))

// Dual 32-long dot for rows r0,r1 of LDS-resident quad-transposed matrix T:
// T[q*128+row] = W[row][4q..4q+3]. 16 ds_read_b128, 8 independent fma chains.
#define DOTL2(RES0, RES1, T, Q) do { \
    float _b0=0.f,_b1=0.f,_b2=0.f,_b3=0.f,_c0=0.f,_c1=0.f,_c2=0.f,_c3=0.f; \
    float4 _w0, _w1; \
    _w0=T[0*128+r0]; _w1=T[0*128+r1]; FMA4F(_b0,_w0,(Q##0)); FMA4F(_c0,_w1,(Q##0)); \
    _w0=T[1*128+r0]; _w1=T[1*128+r1]; FMA4F(_b1,_w0,(Q##1)); FMA4F(_c1,_w1,(Q##1)); \
    _w0=T[2*128+r0]; _w1=T[2*128+r1]; FMA4F(_b2,_w0,(Q##2)); FMA4F(_c2,_w1,(Q##2)); \
    _w0=T[3*128+r0]; _w1=T[3*128+r1]; FMA4F(_b3,_w0,(Q##3)); FMA4F(_c3,_w1,(Q##3)); \
    _w0=T[4*128+r0]; _w1=T[4*128+r1]; FMA4F(_b0,_w0,(Q##4)); FMA4F(_c0,_w1,(Q##4)); \
    _w0=T[5*128+r0]; _w1=T[5*128+r1]; FMA4F(_b1,_w0,(Q##5)); FMA4F(_c1,_w1,(Q##5)); \
    _w0=T[6*128+r0]; _w1=T[6*128+r1]; FMA4F(_b2,_w0,(Q##6)); FMA4F(_c2,_w1,(Q##6)); \
    _w0=T[7*128+r0]; _w1=T[7*128+r1]; FMA4F(_b3,_w0,(Q##7)); FMA4F(_c3,_w1,(Q##7)); \
    RES0=(_b0+_b1)+(_b2+_b3); RES1=(_c0+_c1)+(_c2+_c3); \
} while (0)

// ---------------------------------------------------------------------------
// Kernel A1: emb_proj[v][j] = b_ih1[j]+b_hh1[j] + sum_d emb[v][d]*W_ih1[j][d]
// ---------------------------------------------------------------------------
__global__ __launch_bounds__(128) void emb_proj_kernel(
    const float* __restrict__ emb, const float* __restrict__ W_ih1,
    const float* __restrict__ b_ih1, const float* __restrict__ b_hh1,
    float* __restrict__ emb_proj)
{
    const int v = blockIdx.x;
    const int j = threadIdx.x;
    __shared__ __align__(16) float ev[DD];
    ev[j]       = emb[v * DD + j];
    ev[j + 128] = emb[v * DD + 128 + j];
    __syncthreads();
    float acc = b_ih1[j] + b_hh1[j];
#pragma unroll 8
    for (int q = 0; q < DD / 4; ++q) {
        float4 w = *(const float4*)&W_ih1[j * DD + 4 * q];
        float4 e = *(const float4*)&ev[4 * q];
        acc += w.x * e.x + w.y * e.y + w.z * e.z + w.w * e.w;
    }
    emb_proj[v * G4 + j] = acc;
}

// ---------------------------------------------------------------------------
// Kernel A2: W_fcT[k][v] = W_fc[v][k]
// ---------------------------------------------------------------------------
__global__ __launch_bounds__(256) void transpose_wfc_kernel(
    const float* __restrict__ W_fc, float* __restrict__ W_fcT)
{
    int i = blockIdx.x * 256 + threadIdx.x;
    int v = i >> 5;
    int k = i & 31;
    W_fcT[k * VV + v] = W_fc[i];
}

// ---------------------------------------------------------------------------
// Kernel B: 2-layer LSTM recurrence, one wave per batch element.
// WEIGHTS LIVE IN LDS (quad-transposed, conflict-floor layout), not registers:
// r2-r11 showed the allocator caps ~140 arch VGPRs regardless of launch
// attributes, so 192 resident weight floats always spill -> per-step memory
// round-trips dominate (~2075 cy/step, insensitive to variant). With LDS
// weights, registers hold only h-state + temps (no spills); per-step cost =
// 48 weight ds_read_b128 + 16 broadcast h reads + 192 fma, overlapped pipes.
// ---------------------------------------------------------------------------
__global__ __launch_bounds__(64) void lstm_rec_wave_kernel(
    const int* __restrict__ x_ids, const float* __restrict__ emb_proj,
    const float* __restrict__ W_hh1, const float* __restrict__ W_ih2,
    const float* __restrict__ W_hh2, const float* __restrict__ b_ih2,
    const float* __restrict__ b_hh2, float* __restrict__ h2_all)
{
    const int b = blockIdx.x;
    const int l = threadIdx.x;      // 0..63
    const int half = l >> 5;
    const int r0 = l;
    const int r1 = l + 64;

    // r0 rows (i or f): sigmoid. r1 rows: g (tanh) on half0, o (sigm) on half1.
    const float a1  = half ? 1.0f : 2.0f;   // exp argument scale for r1 act
    const float c1p = half ? 1.0f : 2.0f;   // rcp coefficient for r1 act

    __shared__ __align__(16) float4 T1[1024];   // W_hh1 quad-transposed
    __shared__ __align__(16) float4 T2[1024];   // W_ih2
    __shared__ __align__(16) float4 T3[1024];   // W_hh2
    __shared__ __align__(16) float h1s[HH];
    __shared__ __align__(16) float h2s[HH];

    // ---- stage weights: T[q*128+row] = W[row][4q..4q+3] ----
    {
        const float4* s1 = (const float4*)W_hh1;
        const float4* s2 = (const float4*)W_ih2;
        const float4* s3 = (const float4*)W_hh2;
#pragma unroll
        for (int q = 0; q < 8; ++q) {
#pragma unroll
            for (int rg = 0; rg < 2; ++rg) {
                const int row = rg * 64 + l;
                const int d = q * 128 + row;
                const int s = row * 8 + q;
                T1[d] = s1[s]; T2[d] = s2[s]; T3[d] = s3[s];
            }
        }
    }
    if (l < HH) { h1s[l] = 0.0f; h2s[l] = 0.0f; }
    __syncthreads();

    const float4* h1v = (const float4*)h1s;
    const float4* h2v = (const float4*)h2s;

    DECLH8(h1q); DECLH8(h2q);
    ZEROH(h1q); ZEROH(h2q);

    const float bias20 = b_ih2[r0] + b_hh2[r0];
    const float bias21 = b_ih2[r1] + b_hh2[r1];

    float c1 = 0.0f, c2 = 0.0f;

    const int* ids = x_ids + b * SEQ;
    int idn = ids[1];
    float ep0 = emb_proj[ids[0] * G4 + r0];
    float ep1 = emb_proj[ids[0] * G4 + r1];

    float* h2out = h2_all + (long)b * SEQ * HH + l;

    for (int t = 0; t < SEQ; ++t) {
        // prefetch next step's emb_proj row + id two steps ahead (hidden)
        const float ep0n = emb_proj[idn * G4 + r0];
        const float ep1n = emb_proj[idn * G4 + r1];
        const int tn2 = (t + 2 < SEQ) ? (t + 2) : (SEQ - 1);
        const int idn2 = ids[tn2];

        // ---- layer 1 gates: ep + W_hh1 @ h1(prev) ----
        float d0, d1;
        DOTL2(d0, d1, T1, h1q);
        const float gr0 = ep0 + d0;
        const float gr1 = ep1 + d1;

        const float A0 = fsigm(gr0);
        const float A1 = 1.0f - c1p * __builtin_amdgcn_rcpf(1.0f + __expf(a1 * gr1));
        const float B0 = lane_xor32(A0, half);
        const float B1 = lane_xor32(A1, half);
        const float gi = half ? B0 : A0;
        const float gf = half ? A0 : B0;
        const float gg = half ? B1 : A1;
        const float go = half ? A1 : B1;

        c1 = gf * c1 + gi * gg;
        const float h1n = go * ftanh(c1);

        // publish h1, immediately issue broadcast reads (latency hidden under
        // the independent W_hh2 @ h2(prev) dots)
        if (l < HH) h1s[l] = h1n;
        LOADH(h1q, h1v);

        float p0, p1;
        DOTL2(p0, p1, T3, h2q);

        // ---- layer 2 gates ----
        float e0, e1;
        DOTL2(e0, e1, T2, h1q);
        const float qr0 = bias20 + p0 + e0;
        const float qr1 = bias21 + p1 + e1;

        const float C0 = fsigm(qr0);
        const float C1 = 1.0f - c1p * __builtin_amdgcn_rcpf(1.0f + __expf(a1 * qr1));
        const float D0 = lane_xor32(C0, half);
        const float D1 = lane_xor32(C1, half);
        const float pi = half ? D0 : C0;
        const float pf = half ? C0 : D0;
        const float pg = half ? D1 : C1;
        const float po = half ? C1 : D1;

        c2 = pf * c2 + pi * pg;
        const float h2n = po * ftanh(c2);

        if (l < HH) { h2s[l] = h2n; h2out[t * HH] = h2n; }
        // broadcast h2 for next step (latency hides under next layer-1 dots)
        LOADH(h2q, h2v);

        ep0 = ep0n; ep1 = ep1n; idn = idn2;
    }
}

// ---------------------------------------------------------------------------
// Kernel C: logits = h2 @ W_fc^T + b_fc, row softmax, write [B*S][V].
// r1/r11-proven config: 8 rows/block, 256 threads, 8 vocab cols/thread.
// ---------------------------------------------------------------------------
__global__ __launch_bounds__(256) void fc_softmax_kernel(
    const float* __restrict__ h2_all, const float* __restrict__ W_fcT,
    const float* __restrict__ b_fc, float* __restrict__ out)
{
    const int tid = threadIdx.x;
    const long rowbase = (long)blockIdx.x * 8;
    __shared__ __align__(16) float h2t[8][HH];
    __shared__ float wred[8][4];

    h2t[tid >> 5][tid & 31] = h2_all[rowbase * HH + tid];
    __syncthreads();

    const int v0 = tid * 8;
    const float4 bf0 = *(const float4*)&b_fc[v0];
    const float4 bf1 = *(const float4*)&b_fc[v0 + 4];
    float acc[8][8];
#pragma unroll
    for (int r = 0; r < 8; ++r) {
        acc[r][0] = bf0.x; acc[r][1] = bf0.y; acc[r][2] = bf0.z; acc[r][3] = bf0.w;
        acc[r][4] = bf1.x; acc[r][5] = bf1.y; acc[r][6] = bf1.z; acc[r][7] = bf1.w;
    }

#pragma unroll
    for (int kq = 0; kq < 8; ++kq) {
        const int k = kq * 4;
        float4 wa[4], wb[4];
#pragma unroll
        for (int i = 0; i < 4; ++i) {
            wa[i] = *(const float4*)&W_fcT[(k + i) * VV + v0];
            wb[i] = *(const float4*)&W_fcT[(k + i) * VV + v0 + 4];
        }
#pragma unroll
        for (int r = 0; r < 8; ++r) {
            const float4 h = *(const float4*)&h2t[r][k];
            const float hh[4] = {h.x, h.y, h.z, h.w};
#pragma unroll
            for (int i = 0; i < 4; ++i) {
                acc[r][0] += hh[i] * wa[i].x; acc[r][1] += hh[i] * wa[i].y;
                acc[r][2] += hh[i] * wa[i].z; acc[r][3] += hh[i] * wa[i].w;
                acc[r][4] += hh[i] * wb[i].x; acc[r][5] += hh[i] * wb[i].y;
                acc[r][6] += hh[i] * wb[i].z; acc[r][7] += hh[i] * wb[i].w;
            }
        }
    }

    const int wv = tid >> 6;
    const int lane = tid & 63;

    float m[8];
#pragma unroll
    for (int r = 0; r < 8; ++r) {
        float v = acc[r][0];
#pragma unroll
        for (int c = 1; c < 8; ++c) v = fmaxf(v, acc[r][c]);
#pragma unroll
        for (int s = 32; s >= 1; s >>= 1) v = fmaxf(v, __shfl_xor(v, s, 64));
        m[r] = v;
    }
    if (lane == 0) {
#pragma unroll
        for (int r = 0; r < 8; ++r) wred[r][wv] = m[r];
    }
    __syncthreads();
    float rm[8];
#pragma unroll
    for (int r = 0; r < 8; ++r)
        rm[r] = fmaxf(fmaxf(wred[r][0], wred[r][1]), fmaxf(wred[r][2], wred[r][3]));
    __syncthreads();

    float s[8];
#pragma unroll
    for (int r = 0; r < 8; ++r) {
        float sum = 0.0f;
#pragma unroll
        for (int c = 0; c < 8; ++c) {
            float e = __expf(acc[r][c] - rm[r]);
            acc[r][c] = e;
            sum += e;
        }
#pragma unroll
        for (int st = 32; st >= 1; st >>= 1) sum += __shfl_xor(sum, st, 64);
        s[r] = sum;
    }
    if (lane == 0) {
#pragma unroll
        for (int r = 0; r < 8; ++r) wred[r][wv] = s[r];
    }
    __syncthreads();

#pragma unroll
    for (int r = 0; r < 8; ++r) {
        const float rs = wred[r][0] + wred[r][1] + wred[r][2] + wred[r][3];
        const float inv = 1.0f / rs;
        float4 o0 = make_float4(acc[r][0] * inv, acc[r][1] * inv, acc[r][2] * inv, acc[r][3] * inv);
        float4 o1 = make_float4(acc[r][4] * inv, acc[r][5] * inv, acc[r][6] * inv, acc[r][7] * inv);
        float* op = out + (rowbase + r) * VV + v0;
        *(float4*)op = o0;
        *(float4*)(op + 4) = o1;
    }
}

// ---------------------------------------------------------------------------
extern "C" void kernel_launch(void* const* d_in, const int* in_sizes, int n_in,
                              void* d_out, int out_size, void* d_ws, size_t ws_size,
                              hipStream_t stream)
{
    const int*   x_ids = (const int*)d_in[0];
    const float* emb   = (const float*)d_in[1];
    const float* W_ih1 = (const float*)d_in[2];
    const float* W_hh1 = (const float*)d_in[3];
    const float* b_ih1 = (const float*)d_in[4];
    const float* b_hh1 = (const float*)d_in[5];
    const float* W_ih2 = (const float*)d_in[6];
    const float* W_hh2 = (const float*)d_in[7];
    const float* b_ih2 = (const float*)d_in[8];
    const float* b_hh2 = (const float*)d_in[9];
    const float* W_fc  = (const float*)d_in[10];
    const float* b_fc  = (const float*)d_in[11];
    float* out = (float*)d_out;

    float* ws = (float*)d_ws;
    float* emb_proj = ws;                         // V*4H   = 262144
    float* W_fcT    = ws + 262144;                // H*V    = 65536
    float* h2_all   = ws + 262144 + 65536;        // B*S*H  = 2097152

    emb_proj_kernel<<<VV, 128, 0, stream>>>(emb, W_ih1, b_ih1, b_hh1, emb_proj);
    transpose_wfc_kernel<<<(VV * HH) / 256, 256, 0, stream>>>(W_fc, W_fcT);
    lstm_rec_wave_kernel<<<BB, 64, 0, stream>>>(x_ids, emb_proj, W_hh1, W_ih2, W_hh2,
                                                b_ih2, b_hh2, h2_all);
    fc_softmax_kernel<<<(BB * SEQ) / 8, 256, 0, stream>>>(h2_all, W_fcT, b_fc, out);
}

// Round 13
// 714.987 us; speedup vs baseline: 1.7278x; 1.4802x over previous
//
#include <hip/hip_runtime.h>
#include <cmath>

#define BB   64
#define SEQ  1024
#define DD   256
#define HH   32
#define G4   128   // 4*H
#define VV   2048

// fast sigmoid: e^x/(1+e^x) = 1 - 1/(1+e^x)
__device__ __forceinline__ float fsigm(float x) {
    return 1.0f - __builtin_amdgcn_rcpf(1.0f + __expf(x));
}
// fast tanh: 1 - 2/(1+e^(2x))
__device__ __forceinline__ float ftanh(float x) {
    return 1.0f - 2.0f * __builtin_amdgcn_rcpf(1.0f + __expf(2.0f * x));
}

// y[l] = x[l^32] via v_permlane32_swap (verified r10). With old=src=x:
// r[0]=[x_lo|x_lo], r[1]=[x_hi|x_hi]; lane<32 wants x_hi -> r[1], lane>=32 -> r[0].
__device__ __forceinline__ float lane_xor32(float x, int half) {
#if __has_builtin(__builtin_amdgcn_permlane32_swap)
    auto r = __builtin_amdgcn_permlane32_swap(__float_as_uint(x), __float_as_uint(x),
                                              false, false);
    return __uint_as_float(half ? r[0] : r[1]);
#else
    return __shfl_xor(x, 32, 64);
#endif
}

#define FMA4F(A, W, H) \
    A = fmaf((W).w, (H).w, fmaf((W).z, (H).z, fmaf((W).y, (H).y, fmaf((W).x, (H).x, A))))

// ---------------------------------------------------------------------------
// Kernel A1: emb_proj[v][j] = b_ih1[j]+b_hh1[j] + sum_d emb[v][d]*W_ih1[j][d]
// ---------------------------------------------------------------------------
__global__ __launch_bounds__(128) void emb_proj_kernel(
    const float* __restrict__ emb, const float* __restrict__ W_ih1,
    const float* __restrict__ b_ih1, const float* __restrict__ b_hh1,
    float* __restrict__ emb_proj)
{
    const int v = blockIdx.x;
    const int j = threadIdx.x;
    __shared__ __align__(16) float ev[DD];
    ev[j]       = emb[v * DD + j];
    ev[j + 128] = emb[v * DD + 128 + j];
    __syncthreads();
    float acc = b_ih1[j] + b_hh1[j];
#pragma unroll 8
    for (int q = 0; q < DD / 4; ++q) {
        float4 w = *(const float4*)&W_ih1[j * DD + 4 * q];
        float4 e = *(const float4*)&ev[4 * q];
        acc += w.x * e.x + w.y * e.y + w.z * e.z + w.w * e.w;
    }
    emb_proj[v * G4 + j] = acc;
}

// ---------------------------------------------------------------------------
// Kernel A2: W_fcT[k][v] = W_fc[v][k]
// ---------------------------------------------------------------------------
__global__ __launch_bounds__(256) void transpose_wfc_kernel(
    const float* __restrict__ W_fc, float* __restrict__ W_fcT)
{
    int i = blockIdx.x * 256 + threadIdx.x;
    int v = i >> 5;
    int k = i & 31;
    W_fcT[k * VV + v] = W_fc[i];
}

// ---------------------------------------------------------------------------
// Kernel B: 4-wave pipelined LSTM recurrence. One block (256 thr) per batch.
//   waves 0,1: layer 1 at step t.  waves 2,3: layer 2 at step t-1 (pipelined).
// Lane role: g = (l>>4)&3 (0:i 1:f 2:g~ 3:o), unit u = (l&15)+16*(wid&1),
// row = g*32+u. Each lane owns ONE gate row -> 8 (L1) / 16 (L2) weight quads
// in registers (fits under the allocator cap -> no spills, r2-r12's invariant
// ~2000cy/step cost). Gate exchange is IN-WAVE (shfl_xor16 + permlane32),
// h1/h2 cross-wave via ping-pong LDS with ONE barrier per step. Layer-2's
// dots, LDS reads, and global h2 store are off the critical (layer-1) cycle.
// ---------------------------------------------------------------------------
__global__ __launch_bounds__(256) void lstm_rec_pipe_kernel(
    const int* __restrict__ x_ids, const float* __restrict__ emb_proj,
    const float* __restrict__ W_hh1, const float* __restrict__ W_ih2,
    const float* __restrict__ W_hh2, const float* __restrict__ b_ih2,
    const float* __restrict__ b_hh2, float* __restrict__ h2_all)
{
    const int tid = threadIdx.x;
    const int b   = blockIdx.x;
    const int wid = tid >> 6;          // 0,1 -> layer1; 2,3 -> layer2
    const int l   = tid & 63;
    const int g   = (l >> 4) & 3;      // gate index
    const int half = l >> 5;
    const int u   = (l & 15) + 16 * (wid & 1);
    const int row = g * 32 + u;

    const float aa = (g == 2) ? 2.0f : 1.0f;   // act: 1 - kk*rcp(1+exp(aa*x))
    const float kk = (g == 2) ? 2.0f : 1.0f;
    const bool is_l1 = (wid < 2);
    const int  gbit0 = g & 1, gbit1 = g >> 1;

    // weights: L1 waves -> w=W_hh1[row]; L2 waves -> w=W_ih2[row], v=W_hh2[row]
    float4 w0,w1,w2,w3,w4,w5,w6,w7, v0,v1,v2,v3,v4,v5,v6,v7;
    {
        const float* wsrc = is_l1 ? W_hh1 : W_ih2;
        const float4* pw = (const float4*)&wsrc[row * HH];
        w0=pw[0]; w1=pw[1]; w2=pw[2]; w3=pw[3];
        w4=pw[4]; w5=pw[5]; w6=pw[6]; w7=pw[7];
        const float4* pv = (const float4*)&W_hh2[row * HH];
        v0=pv[0]; v1=pv[1]; v2=pv[2]; v3=pv[3];
        v4=pv[4]; v5=pv[5]; v6=pv[6]; v7=pv[7];
    }
    const float bias2 = b_ih2[row] + b_hh2[row];

    __shared__ __align__(16) float h1s[2][HH];
    __shared__ __align__(16) float h2s[2][HH];
    if (tid < 64) { h1s[tid >> 5][tid & 31] = 0.0f; h2s[tid >> 5][tid & 31] = 0.0f; }
    __syncthreads();

    float cst = 0.0f;                  // c1 (L1 waves) or c2 (L2 waves)
    const int* ids = x_ids + b * SEQ;
    float ep = 0.0f; int idn = 0;
    if (is_l1) {
        ep  = emb_proj[ids[0] * G4 + row];
        idn = ids[1];
    }
    float* h2out = h2_all + (long)b * SEQ * HH;

    for (int t = 0; t <= SEQ; ++t) {
        const int cur = t & 1, nxt = cur ^ 1;
        if (is_l1) {
            if (t < SEQ) {
                // prefetch ep(t+1)
                const float epn = emb_proj[idn * G4 + row];
                const int tn2 = (t + 2 < SEQ) ? (t + 2) : (SEQ - 1);
                const int idn2 = ids[tn2];

                // dot: W_hh1[row] . h1(t-1)   (chain grouping == r10 DOT32S)
                const float4* hv = (const float4*)h1s[cur];
                float a0=0.f, a1=0.f, a2=0.f, a3=0.f;
                float4 q;
                q=hv[0]; FMA4F(a0,w0,q);  q=hv[1]; FMA4F(a1,w1,q);
                q=hv[2]; FMA4F(a2,w2,q);  q=hv[3]; FMA4F(a3,w3,q);
                q=hv[4]; FMA4F(a0,w4,q);  q=hv[5]; FMA4F(a1,w5,q);
                q=hv[6]; FMA4F(a2,w6,q);  q=hv[7]; FMA4F(a3,w7,q);
                const float pre = ep + ((a0 + a1) + (a2 + a3));

                const float A = 1.0f - kk * __builtin_amdgcn_rcpf(1.0f + __expf(aa * pre));
                const float B = __shfl_xor(A, 16, 64);   // gate g^1
                const float C = lane_xor32(A, half);     // gate g^2
                const float D = lane_xor32(B, half);     // gate g^3
                const float gi = gbit1 ? (gbit0 ? D : C) : (gbit0 ? B : A);
                const float gf = gbit1 ? (gbit0 ? C : D) : (gbit0 ? A : B);
                const float gt = gbit1 ? (gbit0 ? B : A) : (gbit0 ? D : C);
                const float go = gbit1 ? (gbit0 ? A : B) : (gbit0 ? C : D);

                cst = gf * cst + gi * gt;
                const float hn = go * ftanh(cst);
                if (g == 0) h1s[nxt][u] = hn;

                ep = epn; idn = idn2;
            }
        } else {
            if (t >= 1) {
                const int s = t - 1;
                // dots: W_ih2[row].h1(s) and W_hh2[row].h2(s-1), r10 combine order
                const float4* h1v = (const float4*)h1s[cur];
                const float4* h2v = (const float4*)h2s[cur];
                float e0=0.f, e1=0.f, e2=0.f, e3=0.f;
                float p0=0.f, p1=0.f, p2=0.f, p3=0.f;
                float4 q;
                q=h1v[0]; FMA4F(e0,w0,q);  q=h1v[1]; FMA4F(e1,w1,q);
                q=h1v[2]; FMA4F(e2,w2,q);  q=h1v[3]; FMA4F(e3,w3,q);
                q=h1v[4]; FMA4F(e0,w4,q);  q=h1v[5]; FMA4F(e1,w5,q);
                q=h1v[6]; FMA4F(e2,w6,q);  q=h1v[7]; FMA4F(e3,w7,q);
                q=h2v[0]; FMA4F(p0,v0,q);  q=h2v[1]; FMA4F(p1,v1,q);
                q=h2v[2]; FMA4F(p2,v2,q);  q=h2v[3]; FMA4F(p3,v3,q);
                q=h2v[4]; FMA4F(p0,v4,q);  q=h2v[5]; FMA4F(p1,v5,q);
                q=h2v[6]; FMA4F(p2,v6,q);  q=h2v[7]; FMA4F(p3,v7,q);
                const float esum = (e0 + e1) + (e2 + e3);
                const float psum = (p0 + p1) + (p2 + p3);
                const float pre = bias2 + psum + esum;

                const float A = 1.0f - kk * __builtin_amdgcn_rcpf(1.0f + __expf(aa * pre));
                const float B = __shfl_xor(A, 16, 64);
                const float C = lane_xor32(A, half);
                const float D = lane_xor32(B, half);
                const float gi = gbit1 ? (gbit0 ? D : C) : (gbit0 ? B : A);
                const float gf = gbit1 ? (gbit0 ? C : D) : (gbit0 ? A : B);
                const float gt = gbit1 ? (gbit0 ? B : A) : (gbit0 ? D : C);
                const float go = gbit1 ? (gbit0 ? A : B) : (gbit0 ? C : D);

                cst = gf * cst + gi * gt;
                const float hn = go * ftanh(cst);
                if (g == 0) {
                    h2s[nxt][u] = hn;
                    h2out[(long)s * HH + u] = hn;
                }
            }
        }
        __syncthreads();
    }
}

// ---------------------------------------------------------------------------
// Kernel C: logits = h2 @ W_fc^T + b_fc, row softmax, write [B*S][V].
// r1/r11-proven config: 8 rows/block, 256 threads, 8 vocab cols/thread.
// ---------------------------------------------------------------------------
__global__ __launch_bounds__(256) void fc_softmax_kernel(
    const float* __restrict__ h2_all, const float* __restrict__ W_fcT,
    const float* __restrict__ b_fc, float* __restrict__ out)
{
    const int tid = threadIdx.x;
    const long rowbase = (long)blockIdx.x * 8;
    __shared__ __align__(16) float h2t[8][HH];
    __shared__ float wred[8][4];

    h2t[tid >> 5][tid & 31] = h2_all[rowbase * HH + tid];
    __syncthreads();

    const int v0 = tid * 8;
    const float4 bf0 = *(const float4*)&b_fc[v0];
    const float4 bf1 = *(const float4*)&b_fc[v0 + 4];
    float acc[8][8];
#pragma unroll
    for (int r = 0; r < 8; ++r) {
        acc[r][0] = bf0.x; acc[r][1] = bf0.y; acc[r][2] = bf0.z; acc[r][3] = bf0.w;
        acc[r][4] = bf1.x; acc[r][5] = bf1.y; acc[r][6] = bf1.z; acc[r][7] = bf1.w;
    }

#pragma unroll
    for (int kq = 0; kq < 8; ++kq) {
        const int k = kq * 4;
        float4 wa[4], wb[4];
#pragma unroll
        for (int i = 0; i < 4; ++i) {
            wa[i] = *(const float4*)&W_fcT[(k + i) * VV + v0];
            wb[i] = *(const float4*)&W_fcT[(k + i) * VV + v0 + 4];
        }
#pragma unroll
        for (int r = 0; r < 8; ++r) {
            const float4 h = *(const float4*)&h2t[r][k];
            const float hh[4] = {h.x, h.y, h.z, h.w};
#pragma unroll
            for (int i = 0; i < 4; ++i) {
                acc[r][0] += hh[i] * wa[i].x; acc[r][1] += hh[i] * wa[i].y;
                acc[r][2] += hh[i] * wa[i].z; acc[r][3] += hh[i] * wa[i].w;
                acc[r][4] += hh[i] * wb[i].x; acc[r][5] += hh[i] * wb[i].y;
                acc[r][6] += hh[i] * wb[i].z; acc[r][7] += hh[i] * wb[i].w;
            }
        }
    }

    const int wv = tid >> 6;
    const int lane = tid & 63;

    float m[8];
#pragma unroll
    for (int r = 0; r < 8; ++r) {
        float v = acc[r][0];
#pragma unroll
        for (int c = 1; c < 8; ++c) v = fmaxf(v, acc[r][c]);
#pragma unroll
        for (int s = 32; s >= 1; s >>= 1) v = fmaxf(v, __shfl_xor(v, s, 64));
        m[r] = v;
    }
    if (lane == 0) {
#pragma unroll
        for (int r = 0; r < 8; ++r) wred[r][wv] = m[r];
    }
    __syncthreads();
    float rm[8];
#pragma unroll
    for (int r = 0; r < 8; ++r)
        rm[r] = fmaxf(fmaxf(wred[r][0], wred[r][1]), fmaxf(wred[r][2], wred[r][3]));
    __syncthreads();

    float s[8];
#pragma unroll
    for (int r = 0; r < 8; ++r) {
        float sum = 0.0f;
#pragma unroll
        for (int c = 0; c < 8; ++c) {
            float e = __expf(acc[r][c] - rm[r]);
            acc[r][c] = e;
            sum += e;
        }
#pragma unroll
        for (int st = 32; st >= 1; st >>= 1) sum += __shfl_xor(sum, st, 64);
        s[r] = sum;
    }
    if (lane == 0) {
#pragma unroll
        for (int r = 0; r < 8; ++r) wred[r][wv] = s[r];
    }
    __syncthreads();

#pragma unroll
    for (int r = 0; r < 8; ++r) {
        const float rs = wred[r][0] + wred[r][1] + wred[r][2] + wred[r][3];
        const float inv = 1.0f / rs;
        float4 o0 = make_float4(acc[r][0] * inv, acc[r][1] * inv, acc[r][2] * inv, acc[r][3] * inv);
        float4 o1 = make_float4(acc[r][4] * inv, acc[r][5] * inv, acc[r][6] * inv, acc[r][7] * inv);
        float* op = out + (rowbase + r) * VV + v0;
        *(float4*)op = o0;
        *(float4*)(op + 4) = o1;
    }
}

// ---------------------------------------------------------------------------
extern "C" void kernel_launch(void* const* d_in, const int* in_sizes, int n_in,
                              void* d_out, int out_size, void* d_ws, size_t ws_size,
                              hipStream_t stream)
{
    const int*   x_ids = (const int*)d_in[0];
    const float* emb   = (const float*)d_in[1];
    const float* W_ih1 = (const float*)d_in[2];
    const float* W_hh1 = (const float*)d_in[3];
    const float* b_ih1 = (const float*)d_in[4];
    const float* b_hh1 = (const float*)d_in[5];
    const float* W_ih2 = (const float*)d_in[6];
    const float* W_hh2 = (const float*)d_in[7];
    const float* b_ih2 = (const float*)d_in[8];
    const float* b_hh2 = (const float*)d_in[9];
    const float* W_fc  = (const float*)d_in[10];
    const float* b_fc  = (const float*)d_in[11];
    float* out = (float*)d_out;

    float* ws = (float*)d_ws;
    float* emb_proj = ws;                         // V*4H   = 262144
    float* W_fcT    = ws + 262144;                // H*V    = 65536
    float* h2_all   = ws + 262144 + 65536;        // B*S*H  = 2097152

    emb_proj_kernel<<<VV, 128, 0, stream>>>(emb, W_ih1, b_ih1, b_hh1, emb_proj);
    transpose_wfc_kernel<<<(VV * HH) / 256, 256, 0, stream>>>(W_fc, W_fcT);
    lstm_rec_pipe_kernel<<<BB, 256, 0, stream>>>(x_ids, emb_proj, W_hh1, W_ih2, W_hh2,
                                                 b_ih2, b_hh2, h2_all);
    fc_softmax_kernel<<<(BB * SEQ) / 8, 256, 0, stream>>>(h2_all, W_fcT, b_fc, out);
}

// Round 14
// 690.516 us; speedup vs baseline: 1.7890x; 1.0354x over previous
//
#include <hip/hip_runtime.h>
#include <cmath>

#define BB   64
#define SEQ  1024
#define DD   256
#define HH   32
#define G4   128   // 4*H
#define VV   2048

// fast tanh: 1 - 2/(1+e^(2x))
__device__ __forceinline__ float ftanh(float x) {
    return 1.0f - 2.0f * __builtin_amdgcn_rcpf(1.0f + __expf(2.0f * x));
}

// y[l] = x[l^32] via v_permlane32_swap (verified r10). With old=src=x:
// r[0]=[x_lo|x_lo], r[1]=[x_hi|x_hi]; lane<32 wants x_hi -> r[1], lane>=32 -> r[0].
__device__ __forceinline__ float lane_xor32(float x, int half) {
#if __has_builtin(__builtin_amdgcn_permlane32_swap)
    auto r = __builtin_amdgcn_permlane32_swap(__float_as_uint(x), __float_as_uint(x),
                                              false, false);
    return __uint_as_float(half ? r[0] : r[1]);
#else
    return __shfl_xor(x, 32, 64);
#endif
}

// y[l] = x[l^16] via v_permlane16_swap (swaps vdst rows 16-31 <-> vsrc rows 0-15
// and 48-63 <-> 32-47). With old=src=x: r[0] = [x0:15|x0:15|x32:47|x32:47],
// r[1] = [x16:31|x16:31|x48:63|x48:63]. Lane with bit4 set wants the lower row
// -> r[0]; bit4 clear wants the upper row -> r[1].
__device__ __forceinline__ float lane_xor16(float x, int l) {
#if __has_builtin(__builtin_amdgcn_permlane16_swap)
    auto r = __builtin_amdgcn_permlane16_swap(__float_as_uint(x), __float_as_uint(x),
                                              false, false);
    return __uint_as_float((l & 16) ? r[0] : r[1]);
#else
    return __shfl_xor(x, 16, 64);
#endif
}

// Barrier that waits only on LDS (lgkmcnt), NOT vmcnt: __syncthreads drains
// vmcnt(0) too, which serializes the per-step h2 global store + emb_proj
// prefetch into every step (guide §5: compiler emits full drain before
// s_barrier). All cross-wave traffic here is LDS, so lgkmcnt(0) suffices.
__device__ __forceinline__ void lds_barrier() {
    asm volatile("s_waitcnt lgkmcnt(0)" ::: "memory");
    __builtin_amdgcn_s_barrier();
}

#define FMA4F(A, W, H) \
    A = fmaf((W).w, (H).w, fmaf((W).z, (H).z, fmaf((W).y, (H).y, fmaf((W).x, (H).x, A))))

// ---------------------------------------------------------------------------
// Kernel A1: emb_proj[v][j] = b_ih1[j]+b_hh1[j] + sum_d emb[v][d]*W_ih1[j][d]
// ---------------------------------------------------------------------------
__global__ __launch_bounds__(128) void emb_proj_kernel(
    const float* __restrict__ emb, const float* __restrict__ W_ih1,
    const float* __restrict__ b_ih1, const float* __restrict__ b_hh1,
    float* __restrict__ emb_proj)
{
    const int v = blockIdx.x;
    const int j = threadIdx.x;
    __shared__ __align__(16) float ev[DD];
    ev[j]       = emb[v * DD + j];
    ev[j + 128] = emb[v * DD + 128 + j];
    __syncthreads();
    float acc = b_ih1[j] + b_hh1[j];
#pragma unroll 8
    for (int q = 0; q < DD / 4; ++q) {
        float4 w = *(const float4*)&W_ih1[j * DD + 4 * q];
        float4 e = *(const float4*)&ev[4 * q];
        acc += w.x * e.x + w.y * e.y + w.z * e.z + w.w * e.w;
    }
    emb_proj[v * G4 + j] = acc;
}

// ---------------------------------------------------------------------------
// Kernel A2: W_fcT[k][v] = W_fc[v][k]
// ---------------------------------------------------------------------------
__global__ __launch_bounds__(256) void transpose_wfc_kernel(
    const float* __restrict__ W_fc, float* __restrict__ W_fcT)
{
    int i = blockIdx.x * 256 + threadIdx.x;
    int v = i >> 5;
    int k = i & 31;
    W_fcT[k * VV + v] = W_fc[i];
}

// ---------------------------------------------------------------------------
// Kernel B: 4-wave pipelined LSTM recurrence (r13 structure). One block
// (256 thr) per batch. waves 0,1: layer 1 step t; waves 2,3: layer 2 step t-1.
// r14 deltas: shfl_xor16 -> v_permlane16_swap (VALU, was ds_permute ~120cy on
// the critical path of BOTH layers); __syncthreads -> lgkmcnt-only barrier
// (keeps h2 global store + ep prefetch in flight across steps).
// ---------------------------------------------------------------------------
__global__ __launch_bounds__(256) void lstm_rec_pipe_kernel(
    const int* __restrict__ x_ids, const float* __restrict__ emb_proj,
    const float* __restrict__ W_hh1, const float* __restrict__ W_ih2,
    const float* __restrict__ W_hh2, const float* __restrict__ b_ih2,
    const float* __restrict__ b_hh2, float* __restrict__ h2_all)
{
    const int tid = threadIdx.x;
    const int b   = blockIdx.x;
    const int wid = tid >> 6;          // 0,1 -> layer1; 2,3 -> layer2
    const int l   = tid & 63;
    const int g   = (l >> 4) & 3;      // gate index
    const int half = l >> 5;
    const int u   = (l & 15) + 16 * (wid & 1);
    const int row = g * 32 + u;

    const float aa = (g == 2) ? 2.0f : 1.0f;   // act: 1 - kk*rcp(1+exp(aa*x))
    const float kk = (g == 2) ? 2.0f : 1.0f;
    const bool is_l1 = (wid < 2);
    const int  gbit0 = g & 1, gbit1 = g >> 1;

    // weights: L1 waves -> w=W_hh1[row]; L2 waves -> w=W_ih2[row], v=W_hh2[row]
    float4 w0,w1,w2,w3,w4,w5,w6,w7, v0,v1,v2,v3,v4,v5,v6,v7;
    {
        const float* wsrc = is_l1 ? W_hh1 : W_ih2;
        const float4* pw = (const float4*)&wsrc[row * HH];
        w0=pw[0]; w1=pw[1]; w2=pw[2]; w3=pw[3];
        w4=pw[4]; w5=pw[5]; w6=pw[6]; w7=pw[7];
        const float4* pv = (const float4*)&W_hh2[row * HH];
        v0=pv[0]; v1=pv[1]; v2=pv[2]; v3=pv[3];
        v4=pv[4]; v5=pv[5]; v6=pv[6]; v7=pv[7];
    }
    const float bias2 = b_ih2[row] + b_hh2[row];

    __shared__ __align__(16) float h1s[2][HH];
    __shared__ __align__(16) float h2s[2][HH];
    if (tid < 64) { h1s[tid >> 5][tid & 31] = 0.0f; h2s[tid >> 5][tid & 31] = 0.0f; }
    __syncthreads();

    float cst = 0.0f;                  // c1 (L1 waves) or c2 (L2 waves)
    const int* ids = x_ids + b * SEQ;
    float ep = 0.0f; int idn = 0;
    if (is_l1) {
        ep  = emb_proj[ids[0] * G4 + row];
        idn = ids[1];
    }
    float* h2out = h2_all + (long)b * SEQ * HH;

    for (int t = 0; t <= SEQ; ++t) {
        const int cur = t & 1, nxt = cur ^ 1;
        if (is_l1) {
            if (t < SEQ) {
                // prefetch ep(t+1) — stays in flight across the counted barrier
                const float epn = emb_proj[idn * G4 + row];
                const int tn2 = (t + 2 < SEQ) ? (t + 2) : (SEQ - 1);
                const int idn2 = ids[tn2];

                // dot: W_hh1[row] . h1(t-1)
                const float4* hv = (const float4*)h1s[cur];
                float a0=0.f, a1=0.f, a2=0.f, a3=0.f;
                float4 q;
                q=hv[0]; FMA4F(a0,w0,q);  q=hv[1]; FMA4F(a1,w1,q);
                q=hv[2]; FMA4F(a2,w2,q);  q=hv[3]; FMA4F(a3,w3,q);
                q=hv[4]; FMA4F(a0,w4,q);  q=hv[5]; FMA4F(a1,w5,q);
                q=hv[6]; FMA4F(a2,w6,q);  q=hv[7]; FMA4F(a3,w7,q);
                const float pre = ep + ((a0 + a1) + (a2 + a3));

                const float A = 1.0f - kk * __builtin_amdgcn_rcpf(1.0f + __expf(aa * pre));
                const float B = lane_xor16(A, l);        // gate g^1
                const float C = lane_xor32(A, half);     // gate g^2
                const float D = lane_xor32(B, half);     // gate g^3
                const float gi = gbit1 ? (gbit0 ? D : C) : (gbit0 ? B : A);
                const float gf = gbit1 ? (gbit0 ? C : D) : (gbit0 ? A : B);
                const float gt = gbit1 ? (gbit0 ? B : A) : (gbit0 ? D : C);
                const float go = gbit1 ? (gbit0 ? A : B) : (gbit0 ? C : D);

                cst = gf * cst + gi * gt;
                const float hn = go * ftanh(cst);
                if (g == 0) h1s[nxt][u] = hn;

                ep = epn; idn = idn2;
            }
        } else {
            if (t >= 1) {
                const int s = t - 1;
                // dots: W_ih2[row].h1(s) and W_hh2[row].h2(s-1)
                const float4* h1v = (const float4*)h1s[cur];
                const float4* h2v = (const float4*)h2s[cur];
                float e0=0.f, e1=0.f, e2=0.f, e3=0.f;
                float p0=0.f, p1=0.f, p2=0.f, p3=0.f;
                float4 q;
                q=h1v[0]; FMA4F(e0,w0,q);  q=h1v[1]; FMA4F(e1,w1,q);
                q=h1v[2]; FMA4F(e2,w2,q);  q=h1v[3]; FMA4F(e3,w3,q);
                q=h1v[4]; FMA4F(e0,w4,q);  q=h1v[5]; FMA4F(e1,w5,q);
                q=h1v[6]; FMA4F(e2,w6,q);  q=h1v[7]; FMA4F(e3,w7,q);
                q=h2v[0]; FMA4F(p0,v0,q);  q=h2v[1]; FMA4F(p1,v1,q);
                q=h2v[2]; FMA4F(p2,v2,q);  q=h2v[3]; FMA4F(p3,v3,q);
                q=h2v[4]; FMA4F(p0,v4,q);  q=h2v[5]; FMA4F(p1,v5,q);
                q=h2v[6]; FMA4F(p2,v6,q);  q=h2v[7]; FMA4F(p3,v7,q);
                const float esum = (e0 + e1) + (e2 + e3);
                const float psum = (p0 + p1) + (p2 + p3);
                const float pre = bias2 + psum + esum;

                const float A = 1.0f - kk * __builtin_amdgcn_rcpf(1.0f + __expf(aa * pre));
                const float B = lane_xor16(A, l);
                const float C = lane_xor32(A, half);
                const float D = lane_xor32(B, half);
                const float gi = gbit1 ? (gbit0 ? D : C) : (gbit0 ? B : A);
                const float gf = gbit1 ? (gbit0 ? C : D) : (gbit0 ? A : B);
                const float gt = gbit1 ? (gbit0 ? B : A) : (gbit0 ? D : C);
                const float go = gbit1 ? (gbit0 ? A : B) : (gbit0 ? C : D);

                cst = gf * cst + gi * gt;
                const float hn = go * ftanh(cst);
                if (g == 0) {
                    h2s[nxt][u] = hn;
                    h2out[(long)s * HH + u] = hn;   // store floats across barrier
                }
            }
        }
        lds_barrier();
    }
}

// ---------------------------------------------------------------------------
// Kernel C: logits = h2 @ W_fc^T + b_fc, row softmax, write [B*S][V].
// r1/r11-proven config: 8 rows/block, 256 threads, 8 vocab cols/thread.
// ---------------------------------------------------------------------------
__global__ __launch_bounds__(256) void fc_softmax_kernel(
    const float* __restrict__ h2_all, const float* __restrict__ W_fcT,
    const float* __restrict__ b_fc, float* __restrict__ out)
{
    const int tid = threadIdx.x;
    const long rowbase = (long)blockIdx.x * 8;
    __shared__ __align__(16) float h2t[8][HH];
    __shared__ float wred[8][4];

    h2t[tid >> 5][tid & 31] = h2_all[rowbase * HH + tid];
    __syncthreads();

    const int v0 = tid * 8;
    const float4 bf0 = *(const float4*)&b_fc[v0];
    const float4 bf1 = *(const float4*)&b_fc[v0 + 4];
    float acc[8][8];
#pragma unroll
    for (int r = 0; r < 8; ++r) {
        acc[r][0] = bf0.x; acc[r][1] = bf0.y; acc[r][2] = bf0.z; acc[r][3] = bf0.w;
        acc[r][4] = bf1.x; acc[r][5] = bf1.y; acc[r][6] = bf1.z; acc[r][7] = bf1.w;
    }

#pragma unroll
    for (int kq = 0; kq < 8; ++kq) {
        const int k = kq * 4;
        float4 wa[4], wb[4];
#pragma unroll
        for (int i = 0; i < 4; ++i) {
            wa[i] = *(const float4*)&W_fcT[(k + i) * VV + v0];
            wb[i] = *(const float4*)&W_fcT[(k + i) * VV + v0 + 4];
        }
#pragma unroll
        for (int r = 0; r < 8; ++r) {
            const float4 h = *(const float4*)&h2t[r][k];
            const float hh[4] = {h.x, h.y, h.z, h.w};
#pragma unroll
            for (int i = 0; i < 4; ++i) {
                acc[r][0] += hh[i] * wa[i].x; acc[r][1] += hh[i] * wa[i].y;
                acc[r][2] += hh[i] * wa[i].z; acc[r][3] += hh[i] * wa[i].w;
                acc[r][4] += hh[i] * wb[i].x; acc[r][5] += hh[i] * wb[i].y;
                acc[r][6] += hh[i] * wb[i].z; acc[r][7] += hh[i] * wb[i].w;
            }
        }
    }

    const int wv = tid >> 6;
    const int lane = tid & 63;

    float m[8];
#pragma unroll
    for (int r = 0; r < 8; ++r) {
        float v = acc[r][0];
#pragma unroll
        for (int c = 1; c < 8; ++c) v = fmaxf(v, acc[r][c]);
#pragma unroll
        for (int s = 32; s >= 1; s >>= 1) v = fmaxf(v, __shfl_xor(v, s, 64));
        m[r] = v;
    }
    if (lane == 0) {
#pragma unroll
        for (int r = 0; r < 8; ++r) wred[r][wv] = m[r];
    }
    __syncthreads();
    float rm[8];
#pragma unroll
    for (int r = 0; r < 8; ++r)
        rm[r] = fmaxf(fmaxf(wred[r][0], wred[r][1]), fmaxf(wred[r][2], wred[r][3]));
    __syncthreads();

    float s[8];
#pragma unroll
    for (int r = 0; r < 8; ++r) {
        float sum = 0.0f;
#pragma unroll
        for (int c = 0; c < 8; ++c) {
            float e = __expf(acc[r][c] - rm[r]);
            acc[r][c] = e;
            sum += e;
        }
#pragma unroll
        for (int st = 32; st >= 1; st >>= 1) sum += __shfl_xor(sum, st, 64);
        s[r] = sum;
    }
    if (lane == 0) {
#pragma unroll
        for (int r = 0; r < 8; ++r) wred[r][wv] = s[r];
    }
    __syncthreads();

#pragma unroll
    for (int r = 0; r < 8; ++r) {
        const float rs = wred[r][0] + wred[r][1] + wred[r][2] + wred[r][3];
        const float inv = 1.0f / rs;
        float4 o0 = make_float4(acc[r][0] * inv, acc[r][1] * inv, acc[r][2] * inv, acc[r][3] * inv);
        float4 o1 = make_float4(acc[r][4] * inv, acc[r][5] * inv, acc[r][6] * inv, acc[r][7] * inv);
        float* op = out + (rowbase + r) * VV + v0;
        *(float4*)op = o0;
        *(float4*)(op + 4) = o1;
    }
}

// ---------------------------------------------------------------------------
extern "C" void kernel_launch(void* const* d_in, const int* in_sizes, int n_in,
                              void* d_out, int out_size, void* d_ws, size_t ws_size,
                              hipStream_t stream)
{
    const int*   x_ids = (const int*)d_in[0];
    const float* emb   = (const float*)d_in[1];
    const float* W_ih1 = (const float*)d_in[2];
    const float* W_hh1 = (const float*)d_in[3];
    const float* b_ih1 = (const float*)d_in[4];
    const float* b_hh1 = (const float*)d_in[5];
    const float* W_ih2 = (const float*)d_in[6];
    const float* W_hh2 = (const float*)d_in[7];
    const float* b_ih2 = (const float*)d_in[8];
    const float* b_hh2 = (const float*)d_in[9];
    const float* W_fc  = (const float*)d_in[10];
    const float* b_fc  = (const float*)d_in[11];
    float* out = (float*)d_out;

    float* ws = (float*)d_ws;
    float* emb_proj = ws;                         // V*4H   = 262144
    float* W_fcT    = ws + 262144;                // H*V    = 65536
    float* h2_all   = ws + 262144 + 65536;        // B*S*H  = 2097152

    emb_proj_kernel<<<VV, 128, 0, stream>>>(emb, W_ih1, b_ih1, b_hh1, emb_proj);
    transpose_wfc_kernel<<<(VV * HH) / 256, 256, 0, stream>>>(W_fc, W_fcT);
    lstm_rec_pipe_kernel<<<BB, 256, 0, stream>>>(x_ids, emb_proj, W_hh1, W_ih2, W_hh2,
                                                 b_ih2, b_hh2, h2_all);
    fc_softmax_kernel<<<(BB * SEQ) / 8, 256, 0, stream>>>(h2_all, W_fcT, b_fc, out);
}